// Round 1
// baseline (1198.433 us; speedup 1.0000x reference)
//
#include <hip/hip_runtime.h>
#include <hip/hip_bf16.h>
#include <math.h>

#define N_ROI 512
#define N_POS 128
#define NUM_CLS 81
#define OUTSZ 7
#define CCH 256
#define KDIM (CCH * OUTSZ * OUTSZ)   // 12544
#define HID 1024

// ---------------------------------------------------------------------------
// ROI align at the selected FPN level only (one-hot einsum == level select).
// One block per ROI, 256 threads = 256 channels. Sample-point geometry is
// computed once into LDS (14 x-samples, 14 y-samples).
// ---------------------------------------------------------------------------
__global__ __launch_bounds__(256) void roi_align_kernel(
    const float* __restrict__ P2, const float* __restrict__ P3,
    const float* __restrict__ P4, const float* __restrict__ P5,
    const float* __restrict__ rois, float* __restrict__ xout) {
  int n = blockIdx.x;
  int t = threadIdx.x;

  float rx1 = rois[n * 4 + 0], ry1 = rois[n * 4 + 1];
  float rx2 = rois[n * 4 + 2], ry2 = rois[n * 4 + 3];
  float area = (rx2 - rx1 + 1.0f) * (ry2 - ry1 + 1.0f);
  float lf = floorf(4.0f + log2f(sqrtf(area) / 224.0f));
  lf = fminf(fmaxf(lf, 2.0f), 5.0f);
  int lvl = (int)lf - 2;

  const float scales[4] = {0.25f, 0.125f, 0.0625f, 0.03125f};
  const int   Hs[4] = {200, 100, 50, 25};
  const int   Ws[4] = {256, 128, 64, 32};
  const float* feats[4] = {P2, P3, P4, P5};
  float sc = scales[lvl];
  int H = Hs[lvl], W = Ws[lvl];
  const float* feat = feats[lvl];

  float bx1 = rx1 * sc, by1 = ry1 * sc;
  float bx2 = rx2 * sc, by2 = ry2 * sc;
  float bw = fmaxf(bx2 - bx1, 1.0f) * (1.0f / 7.0f);
  float bh = fmaxf(by2 - by1, 1.0f) * (1.0f / 7.0f);

  __shared__ int   sx0[14], sx1[14], sy0[14], sy1[14];
  __shared__ float slx[14], sly[14], svx[14], svy[14];
  if (t < 14) {
    int i = t >> 1, s = t & 1;
    float g = (float)i + ((float)s + 0.5f) * 0.5f;
    // x sample
    float px = bx1 + g * bw;
    svx[t] = (px > -1.0f && px < (float)W) ? 1.0f : 0.0f;
    float xx = fminf(fmaxf(px, 0.0f), (float)(W - 1));
    float x0f = floorf(xx);
    sx0[t] = (int)x0f;
    sx1[t] = min((int)x0f + 1, W - 1);
    slx[t] = xx - x0f;
    // y sample
    float py = by1 + g * bh;
    svy[t] = (py > -1.0f && py < (float)H) ? 1.0f : 0.0f;
    float yy = fminf(fmaxf(py, 0.0f), (float)(H - 1));
    float y0f = floorf(yy);
    sy0[t] = (int)y0f;
    sy1[t] = min((int)y0f + 1, H - 1);
    sly[t] = yy - y0f;
  }
  __syncthreads();

  int c = t;
  const float* fc = feat + (size_t)c * H * W;
  float* outp = xout + (size_t)n * KDIM + (size_t)c * 49;
  for (int j = 0; j < 49; ++j) {
    int oh = j / 7, ow = j % 7;
    float acc = 0.0f;
#pragma unroll
    for (int sy = 0; sy < 2; ++sy) {
      int iy = oh * 2 + sy;
      int y0 = sy0[iy], y1 = sy1[iy];
      float ly = sly[iy], vy = svy[iy];
#pragma unroll
      for (int sx = 0; sx < 2; ++sx) {
        int ix = ow * 2 + sx;
        int x0 = sx0[ix], x1 = sx1[ix];
        float lx = slx[ix];
        float v = vy * svx[ix];
        float f00 = fc[y0 * W + x0], f01 = fc[y0 * W + x1];
        float f10 = fc[y1 * W + x0], f11 = fc[y1 * W + x1];
        float bil = f00 * (1.0f - ly) * (1.0f - lx) + f01 * (1.0f - ly) * lx +
                    f10 * ly * (1.0f - lx) + f11 * ly * lx;
        acc += bil * v;
      }
    }
    outp[j] = acc * 0.25f;
  }
}

// ---------------------------------------------------------------------------
// fp32 tiled GEMM: C[M,N] = act(A[M,K] @ B[K,N] + bias). BM=32 BN=64 BK=32,
// 256 threads, 2x4 micro-tile per thread. M%32==0, N%64==0, K%32==0 assumed.
// ---------------------------------------------------------------------------
#define BM 32
#define BN 64
#define BK 32
__global__ __launch_bounds__(256) void gemm_bias_act(
    const float* __restrict__ A, const float* __restrict__ B,
    const float* __restrict__ bias, float* __restrict__ C,
    int M, int N, int K, int relu) {
  __shared__ float As[BM][BK + 1];
  __shared__ float Bs[BK][BN];

  int t = threadIdx.x;
  int tx = t & 15;        // 0..15 -> 4 cols each
  int ty = t >> 4;        // 0..15 -> 2 rows each
  int bm = blockIdx.y * BM;
  int bn = blockIdx.x * BN;

  float acc[2][4] = {{0.f, 0.f, 0.f, 0.f}, {0.f, 0.f, 0.f, 0.f}};

  for (int k0 = 0; k0 < K; k0 += BK) {
#pragma unroll
    for (int p = 0; p < 4; ++p) {
      int r = (t >> 5) + p * 8;
      int kk = t & 31;
      As[r][kk] = A[(size_t)(bm + r) * K + k0 + kk];
    }
#pragma unroll
    for (int p = 0; p < 8; ++p) {
      int kk = (t >> 6) + p * 4;
      int nn = t & 63;
      Bs[kk][nn] = B[(size_t)(k0 + kk) * N + bn + nn];
    }
    __syncthreads();
#pragma unroll
    for (int kk = 0; kk < BK; ++kk) {
      float a0 = As[ty * 2 + 0][kk];
      float a1 = As[ty * 2 + 1][kk];
      float4 b = *(const float4*)&Bs[kk][tx * 4];
      acc[0][0] += a0 * b.x; acc[0][1] += a0 * b.y;
      acc[0][2] += a0 * b.z; acc[0][3] += a0 * b.w;
      acc[1][0] += a1 * b.x; acc[1][1] += a1 * b.y;
      acc[1][2] += a1 * b.z; acc[1][3] += a1 * b.w;
    }
    __syncthreads();
  }

#pragma unroll
  for (int r = 0; r < 2; ++r) {
#pragma unroll
    for (int i = 0; i < 4; ++i) {
      int row = bm + ty * 2 + r;
      int col = bn + tx * 4 + i;
      float v = acc[r][i] + bias[col];
      if (relu) v = fmaxf(v, 0.0f);
      C[(size_t)row * N + col] = v;
    }
  }
}

// ---------------------------------------------------------------------------
// logits[n][j] = h2[n] . Wcls[:,j] + bcls[j];  one block per row.
// ---------------------------------------------------------------------------
__global__ __launch_bounds__(128) void cls_head_kernel(
    const float* __restrict__ h2, const float* __restrict__ Wcls,
    const float* __restrict__ bcls, float* __restrict__ logits) {
  __shared__ float hrow[HID];
  int n = blockIdx.x;
  for (int k = threadIdx.x; k < HID; k += 128) hrow[k] = h2[(size_t)n * HID + k];
  __syncthreads();
  int j = threadIdx.x;
  if (j < NUM_CLS) {
    float s = bcls[j];
#pragma unroll 8
    for (int k = 0; k < HID; ++k) s += hrow[k] * Wcls[(size_t)k * NUM_CLS + j];
    logits[(size_t)n * NUM_CLS + j] = s;
  }
}

// ---------------------------------------------------------------------------
// loc_train[n][d] = h2[n] . Wloc[:, label[n]*4+d] + bloc[label[n]*4+d]
// Only n < 128 is consumed. One block per n; wave w handles d=w.
// ---------------------------------------------------------------------------
__global__ __launch_bounds__(256) void loc_head_kernel(
    const float* __restrict__ h2, const float* __restrict__ Wloc,
    const float* __restrict__ bloc, const int* __restrict__ label,
    float* __restrict__ loct) {
  int n = blockIdx.x;
  int d = threadIdx.x >> 6;       // 0..3
  int lane = threadIdx.x & 63;
  int lab = label[n];
  const float* h = h2 + (size_t)n * HID;
  const float* w = Wloc + (size_t)lab * 4 + d;
  float s = 0.0f;
#pragma unroll
  for (int i = 0; i < 16; ++i) {
    int k = lane + i * 64;
    s += h[k] * w[(size_t)k * (NUM_CLS * 4)];
  }
#pragma unroll
  for (int off = 32; off > 0; off >>= 1) s += __shfl_down(s, off);
  if (lane == 0) loct[n * 4 + d] = s + bloc[lab * 4 + d];
}

// ---------------------------------------------------------------------------
// Final fused loss: per-row log-softmax NLL (mean over 512) + smooth-L1
// (sum over 128x4, / 512). One block, 512 threads, thread t = row t and
// also box element t.
// ---------------------------------------------------------------------------
__global__ __launch_bounds__(512) void loss_kernel(
    const float* __restrict__ logits, const int* __restrict__ label,
    const float* __restrict__ loct, const float* __restrict__ loc,
    float* __restrict__ out) {
  int t = threadIdx.x;
  const float* row = logits + (size_t)t * NUM_CLS;
  float m = -1e30f;
  for (int j = 0; j < NUM_CLS; ++j) m = fmaxf(m, row[j]);
  float se = 0.0f;
  for (int j = 0; j < NUM_CLS; ++j) se += expf(row[j] - m);
  float cl = (m + logf(se)) - row[label[t]];

  float a = fabsf(loct[t] - loc[t]);   // t in [0,512) covers 128x4 exactly
  float bl = (a < 1.0f) ? 0.5f * a * a : a - 0.5f;

  float v = cl + bl;
#pragma unroll
  for (int off = 32; off > 0; off >>= 1) v += __shfl_down(v, off);

  __shared__ float red[8];
  if ((t & 63) == 0) red[t >> 6] = v;
  __syncthreads();
  if (t == 0) {
    float tot = 0.0f;
    for (int i = 0; i < 8; ++i) tot += red[i];
    out[0] = tot * (1.0f / (float)N_ROI);
  }
}

// ---------------------------------------------------------------------------
extern "C" void kernel_launch(void* const* d_in, const int* in_sizes, int n_in,
                              void* d_out, int out_size, void* d_ws, size_t ws_size,
                              hipStream_t stream) {
  const float* P2   = (const float*)d_in[0];
  const float* P3   = (const float*)d_in[1];
  const float* P4   = (const float*)d_in[2];
  const float* P5   = (const float*)d_in[3];
  const float* rois = (const float*)d_in[4];
  const int*   label= (const int*)d_in[5];
  const float* loc  = (const float*)d_in[6];
  const float* W1   = (const float*)d_in[7];
  const float* b1   = (const float*)d_in[8];
  const float* W2   = (const float*)d_in[9];
  const float* b2   = (const float*)d_in[10];
  const float* Wcls = (const float*)d_in[11];
  const float* bcls = (const float*)d_in[12];
  const float* Wloc = (const float*)d_in[13];
  const float* bloc = (const float*)d_in[14];
  float* out = (float*)d_out;

  float* x      = (float*)d_ws;                         // 512*12544
  float* h1     = x + (size_t)N_ROI * KDIM;             // 512*1024
  float* h2     = h1 + (size_t)N_ROI * HID;             // 512*1024
  float* logits = h2 + (size_t)N_ROI * HID;             // 512*81
  float* loct   = logits + (size_t)N_ROI * NUM_CLS;     // 512

  roi_align_kernel<<<N_ROI, 256, 0, stream>>>(P2, P3, P4, P5, rois, x);

  gemm_bias_act<<<dim3(HID / BN, N_ROI / BM), 256, 0, stream>>>(
      x, W1, b1, h1, N_ROI, HID, KDIM, 1);
  gemm_bias_act<<<dim3(HID / BN, N_ROI / BM), 256, 0, stream>>>(
      h1, W2, b2, h2, N_ROI, HID, HID, 1);

  cls_head_kernel<<<N_ROI, 128, 0, stream>>>(h2, Wcls, bcls, logits);
  loc_head_kernel<<<N_POS, 256, 0, stream>>>(h2, Wloc, bloc, label, loct);
  loss_kernel<<<1, 512, 0, stream>>>(logits, label, loct, loc, out);
}

// Round 2
// 493.639 us; speedup vs baseline: 2.4278x; 2.4278x over previous
//
#include <hip/hip_runtime.h>
#include <hip/hip_bf16.h>
#include <math.h>

#define N_ROI 512
#define N_POS 128
#define NUM_CLS 81
#define KDIM 12544          // 256 ch * 7 * 7
#define HID 1024

typedef __bf16 bf16x8 __attribute__((ext_vector_type(8)));
typedef float f32x4 __attribute__((ext_vector_type(4)));

// ---------------------------------------------------------------------------
// ROI align at the selected FPN level (one-hot einsum == level select).
// One wave = one (ROI, channel); lanes = 49 output cells. Gathers within a
// wave stay inside one feature plane -> shared cache lines.
// Writes x directly as bf16 [512][12544] (c*49 + cell layout matches
// reference reshape of (N,C,7,7)).
// ---------------------------------------------------------------------------
__global__ __launch_bounds__(256) void roi_align_kernel(
    const float* __restrict__ P2, const float* __restrict__ P3,
    const float* __restrict__ P4, const float* __restrict__ P5,
    const float* __restrict__ rois, __bf16* __restrict__ xout) {
  int n = blockIdx.x;
  int ch = blockIdx.y * 4 + (threadIdx.x >> 6);
  int lane = threadIdx.x & 63;

  float rx1 = rois[n * 4 + 0], ry1 = rois[n * 4 + 1];
  float rx2 = rois[n * 4 + 2], ry2 = rois[n * 4 + 3];
  float area = (rx2 - rx1 + 1.0f) * (ry2 - ry1 + 1.0f);
  float lf = floorf(4.0f + log2f(sqrtf(area) / 224.0f));
  lf = fminf(fmaxf(lf, 2.0f), 5.0f);
  int lvl = (int)lf - 2;

  const float scales[4] = {0.25f, 0.125f, 0.0625f, 0.03125f};
  const int   Hs[4] = {200, 100, 50, 25};
  const int   Ws[4] = {256, 128, 64, 32};
  const float* feats[4] = {P2, P3, P4, P5};
  float sc = scales[lvl];
  int H = Hs[lvl], W = Ws[lvl];
  const float* feat = feats[lvl];

  float bx1 = rx1 * sc, by1 = ry1 * sc;
  float bw = fmaxf(rx2 * sc - bx1, 1.0f) * (1.0f / 7.0f);
  float bh = fmaxf(ry2 * sc - by1, 1.0f) * (1.0f / 7.0f);

  if (lane >= 49) return;
  int oh = (lane * 37) >> 8;       // floor(lane/7) for lane<49
  int ow = lane - oh * 7;

  const float* fc = feat + (size_t)ch * H * W;
  float acc = 0.0f;
#pragma unroll
  for (int sy = 0; sy < 2; ++sy) {
    float py = by1 + ((float)oh + ((float)sy + 0.5f) * 0.5f) * bh;
    float vy = (py > -1.0f && py < (float)H) ? 1.0f : 0.0f;
    float yy = fminf(fmaxf(py, 0.0f), (float)(H - 1));
    float y0f = floorf(yy);
    int y0 = (int)y0f;
    int y1 = min(y0 + 1, H - 1);
    float ly = yy - y0f;
#pragma unroll
    for (int sx = 0; sx < 2; ++sx) {
      float px = bx1 + ((float)ow + ((float)sx + 0.5f) * 0.5f) * bw;
      float v = vy * ((px > -1.0f && px < (float)W) ? 1.0f : 0.0f);
      float xx = fminf(fmaxf(px, 0.0f), (float)(W - 1));
      float x0f = floorf(xx);
      int x0 = (int)x0f;
      int x1 = min(x0 + 1, W - 1);
      float lx = xx - x0f;
      float f00 = fc[y0 * W + x0], f01 = fc[y0 * W + x1];
      float f10 = fc[y1 * W + x0], f11 = fc[y1 * W + x1];
      float bil = f00 * (1.0f - ly) * (1.0f - lx) + f01 * (1.0f - ly) * lx +
                  f10 * ly * (1.0f - lx) + f11 * ly * lx;
      acc += bil * v;
    }
  }
  xout[(size_t)n * KDIM + (size_t)ch * 49 + lane] = (__bf16)(acc * 0.25f);
}

// ---------------------------------------------------------------------------
// Tiled transpose + fp32->bf16: src [R][C] fp32 -> dst [C][R] bf16.
// ---------------------------------------------------------------------------
__global__ __launch_bounds__(256) void transpose_to_bf16(
    const float* __restrict__ src, __bf16* __restrict__ dst, int R, int C) {
  __shared__ float tile[32][33];
  int bc = blockIdx.x * 32, br = blockIdx.y * 32;
  int tx = threadIdx.x & 31, ty = threadIdx.x >> 5;  // ty 0..7
#pragma unroll
  for (int i = 0; i < 32; i += 8)
    tile[ty + i][tx] = src[(size_t)(br + ty + i) * C + bc + tx];
  __syncthreads();
#pragma unroll
  for (int i = 0; i < 32; i += 8)
    dst[(size_t)(bc + ty + i) * R + br + tx] = (__bf16)tile[tx][ty + i];
}

// ---------------------------------------------------------------------------
// bf16 MFMA GEMM: C[M][N] = act(A[M][K] @ Bt[N][K]^T + bias).
// 64x64 tile, 256 threads (4 waves, each 32x32 via 2x2 of 16x16x32 mfma).
// LDS row stride 40 shorts (80B = 20 banks) -> 2-way aliasing only (free).
// Output to fp32 (Cf) and/or bf16 (Cb).
// ---------------------------------------------------------------------------
#define LDA 40
__global__ __launch_bounds__(256) void mfma_gemm(
    const __bf16* __restrict__ A, const __bf16* __restrict__ Bt,
    const float* __restrict__ bias, float* __restrict__ Cf,
    __bf16* __restrict__ Cb, int M, int N, int K, int relu) {
  __shared__ __align__(16) __bf16 As[64 * LDA];
  __shared__ __align__(16) __bf16 Bs[64 * LDA];

  int t = threadIdx.x;
  int bm = blockIdx.y * 64, bn = blockIdx.x * 64;
  int wave = t >> 6, lane = t & 63;
  int wm = (wave >> 1) * 32, wn = (wave & 1) * 32;

  // staging: thread t loads row t>>2, k-chunk (t&3)*8 (16B each)
  int lr = t >> 2;
  int lc = (t & 3) * 8;
  const __bf16* Aptr = A + (size_t)(bm + lr) * K + lc;
  const __bf16* Bptr = Bt + (size_t)(bn + lr) * K + lc;
  int stoff = lr * LDA + lc;

  int fr = lane & 15, q = lane >> 4;

  f32x4 acc[2][2];
#pragma unroll
  for (int i = 0; i < 2; ++i)
#pragma unroll
    for (int j = 0; j < 2; ++j) acc[i][j] = (f32x4){0.f, 0.f, 0.f, 0.f};

  for (int k0 = 0; k0 < K; k0 += 32) {
    bf16x8 av = *(const bf16x8*)Aptr;
    bf16x8 bv = *(const bf16x8*)Bptr;
    Aptr += 32;
    Bptr += 32;
    __syncthreads();
    *(bf16x8*)&As[stoff] = av;
    *(bf16x8*)&Bs[stoff] = bv;
    __syncthreads();

    bf16x8 af[2], bf[2];
    af[0] = *(const bf16x8*)&As[(wm + fr) * LDA + q * 8];
    af[1] = *(const bf16x8*)&As[(wm + 16 + fr) * LDA + q * 8];
    bf[0] = *(const bf16x8*)&Bs[(wn + fr) * LDA + q * 8];
    bf[1] = *(const bf16x8*)&Bs[(wn + 16 + fr) * LDA + q * 8];
#pragma unroll
    for (int i = 0; i < 2; ++i)
#pragma unroll
      for (int j = 0; j < 2; ++j)
        acc[i][j] = __builtin_amdgcn_mfma_f32_16x16x32_bf16(af[i], bf[j],
                                                            acc[i][j], 0, 0, 0);
  }

  // epilogue: D row = q*4 + reg, col = lane&15
#pragma unroll
  for (int i = 0; i < 2; ++i) {
#pragma unroll
    for (int j = 0; j < 2; ++j) {
      int colg = bn + wn + j * 16 + fr;
      float bv = bias[colg];
      int rowb = bm + wm + i * 16 + q * 4;
#pragma unroll
      for (int r = 0; r < 4; ++r) {
        float v = acc[i][j][r] + bv;
        if (relu) v = fmaxf(v, 0.0f);
        size_t idx = (size_t)(rowb + r) * N + colg;
        if (Cf) Cf[idx] = v;
        if (Cb) Cb[idx] = (__bf16)v;
      }
    }
  }
}

// ---------------------------------------------------------------------------
// logits[n][j] = h2[n] . Wcls[:,j] + bcls[j];  one block per row.
// ---------------------------------------------------------------------------
__global__ __launch_bounds__(128) void cls_head_kernel(
    const float* __restrict__ h2, const float* __restrict__ Wcls,
    const float* __restrict__ bcls, float* __restrict__ logits) {
  __shared__ float hrow[HID];
  int n = blockIdx.x;
  for (int k = threadIdx.x; k < HID; k += 128) hrow[k] = h2[(size_t)n * HID + k];
  __syncthreads();
  int j = threadIdx.x;
  if (j < NUM_CLS) {
    float s = bcls[j];
#pragma unroll 8
    for (int k = 0; k < HID; ++k) s += hrow[k] * Wcls[(size_t)k * NUM_CLS + j];
    logits[(size_t)n * NUM_CLS + j] = s;
  }
}

// ---------------------------------------------------------------------------
// loc_train[n][d] = h2[n] . Wloc[:, label[n]*4+d] + bloc[label[n]*4+d]
// ---------------------------------------------------------------------------
__global__ __launch_bounds__(256) void loc_head_kernel(
    const float* __restrict__ h2, const float* __restrict__ Wloc,
    const float* __restrict__ bloc, const int* __restrict__ label,
    float* __restrict__ loct) {
  int n = blockIdx.x;
  int d = threadIdx.x >> 6;  // 0..3
  int lane = threadIdx.x & 63;
  int lab = label[n];
  const float* h = h2 + (size_t)n * HID;
  const float* w = Wloc + (size_t)lab * 4 + d;
  float s = 0.0f;
#pragma unroll
  for (int i = 0; i < 16; ++i) {
    int k = lane + i * 64;
    s += h[k] * w[(size_t)k * (NUM_CLS * 4)];
  }
#pragma unroll
  for (int off = 32; off > 0; off >>= 1) s += __shfl_down(s, off);
  if (lane == 0) loct[n * 4 + d] = s + bloc[lab * 4 + d];
}

// ---------------------------------------------------------------------------
// Fused loss: log-softmax NLL (mean over 512) + smooth-L1 (sum/512).
// ---------------------------------------------------------------------------
__global__ __launch_bounds__(512) void loss_kernel(
    const float* __restrict__ logits, const int* __restrict__ label,
    const float* __restrict__ loct, const float* __restrict__ loc,
    float* __restrict__ out) {
  int t = threadIdx.x;
  const float* row = logits + (size_t)t * NUM_CLS;
  float m = -1e30f;
  for (int j = 0; j < NUM_CLS; ++j) m = fmaxf(m, row[j]);
  float se = 0.0f;
  for (int j = 0; j < NUM_CLS; ++j) se += expf(row[j] - m);
  float cl = (m + logf(se)) - row[label[t]];

  float a = fabsf(loct[t] - loc[t]);  // t in [0,512) == 128x4
  float bl = (a < 1.0f) ? 0.5f * a * a : a - 0.5f;

  float v = cl + bl;
#pragma unroll
  for (int off = 32; off > 0; off >>= 1) v += __shfl_down(v, off);

  __shared__ float red[8];
  if ((t & 63) == 0) red[t >> 6] = v;
  __syncthreads();
  if (t == 0) {
    float tot = 0.0f;
    for (int i = 0; i < 8; ++i) tot += red[i];
    out[0] = tot * (1.0f / (float)N_ROI);
  }
}

// ---------------------------------------------------------------------------
extern "C" void kernel_launch(void* const* d_in, const int* in_sizes, int n_in,
                              void* d_out, int out_size, void* d_ws, size_t ws_size,
                              hipStream_t stream) {
  const float* P2   = (const float*)d_in[0];
  const float* P3   = (const float*)d_in[1];
  const float* P4   = (const float*)d_in[2];
  const float* P5   = (const float*)d_in[3];
  const float* rois = (const float*)d_in[4];
  const int*   label= (const int*)d_in[5];
  const float* loc  = (const float*)d_in[6];
  const float* W1   = (const float*)d_in[7];
  const float* b1   = (const float*)d_in[8];
  const float* W2   = (const float*)d_in[9];
  const float* b2   = (const float*)d_in[10];
  const float* Wcls = (const float*)d_in[11];
  const float* bcls = (const float*)d_in[12];
  const float* Wloc = (const float*)d_in[13];
  const float* bloc = (const float*)d_in[14];
  float* out = (float*)d_out;

  __bf16* xb  = (__bf16*)d_ws;                        // 512*12544
  __bf16* W1t = xb + (size_t)N_ROI * KDIM;            // 1024*12544
  __bf16* W2t = W1t + (size_t)KDIM * HID;             // 1024*1024
  __bf16* h1b = W2t + (size_t)HID * HID;              // 512*1024
  float*  h2  = (float*)(h1b + (size_t)N_ROI * HID);  // 512*1024 fp32
  float*  logits = h2 + (size_t)N_ROI * HID;          // 512*81
  float*  loct   = logits + (size_t)N_ROI * NUM_CLS;  // 512

  transpose_to_bf16<<<dim3(HID / 32, KDIM / 32), 256, 0, stream>>>(W1, W1t,
                                                                   KDIM, HID);
  transpose_to_bf16<<<dim3(HID / 32, HID / 32), 256, 0, stream>>>(W2, W2t,
                                                                  HID, HID);
  roi_align_kernel<<<dim3(N_ROI, 64), 256, 0, stream>>>(P2, P3, P4, P5, rois,
                                                        xb);
  // FC1: [512,12544] @ [12544,1024] -> h1 (bf16, relu)
  mfma_gemm<<<dim3(HID / 64, N_ROI / 64), 256, 0, stream>>>(
      xb, W1t, b1, nullptr, h1b, N_ROI, HID, KDIM, 1);
  // FC2: [512,1024] @ [1024,1024] -> h2 (fp32, relu)
  mfma_gemm<<<dim3(HID / 64, N_ROI / 64), 256, 0, stream>>>(
      h1b, W2t, b2, h2, nullptr, N_ROI, HID, HID, 1);

  cls_head_kernel<<<N_ROI, 128, 0, stream>>>(h2, Wcls, bcls, logits);
  loc_head_kernel<<<N_POS, 256, 0, stream>>>(h2, Wloc, bloc, label, loct);
  loss_kernel<<<1, 512, 0, stream>>>(logits, label, loct, loc, out);
}

// Round 3
// 319.667 us; speedup vs baseline: 3.7490x; 1.5442x over previous
//
#include <hip/hip_runtime.h>
#include <hip/hip_bf16.h>
#include <math.h>

#define N_ROI 512
#define N_POS 128
#define NUM_CLS 81
#define KDIM 12544          // 256 ch * 7 * 7
#define HID 1024

typedef __bf16 bf16x8 __attribute__((ext_vector_type(8)));
typedef __bf16 bf16x4 __attribute__((ext_vector_type(4)));
typedef float f32x4 __attribute__((ext_vector_type(4)));

__device__ inline void gload16(const void* g, void* lds) {
  __builtin_amdgcn_global_load_lds(
      (const __attribute__((address_space(1))) void*)g,
      (__attribute__((address_space(3))) void*)lds, 16, 0, 0);
}

// ---------------------------------------------------------------------------
// ROI align at the selected FPN level (one-hot einsum == level select).
// One wave = one (ROI, channel); lanes 0..48 = the 49 output cells.
// ---------------------------------------------------------------------------
__global__ __launch_bounds__(256) void roi_align_kernel(
    const float* __restrict__ P2, const float* __restrict__ P3,
    const float* __restrict__ P4, const float* __restrict__ P5,
    const float* __restrict__ rois, __bf16* __restrict__ xout) {
  int n = blockIdx.x;
  int ch = blockIdx.y * 4 + (threadIdx.x >> 6);
  int lane = threadIdx.x & 63;

  float rx1 = rois[n * 4 + 0], ry1 = rois[n * 4 + 1];
  float rx2 = rois[n * 4 + 2], ry2 = rois[n * 4 + 3];
  float area = (rx2 - rx1 + 1.0f) * (ry2 - ry1 + 1.0f);
  float lf = floorf(4.0f + log2f(sqrtf(area) / 224.0f));
  lf = fminf(fmaxf(lf, 2.0f), 5.0f);
  int lvl = (int)lf - 2;

  const float scales[4] = {0.25f, 0.125f, 0.0625f, 0.03125f};
  const int   Hs[4] = {200, 100, 50, 25};
  const int   Ws[4] = {256, 128, 64, 32};
  const float* feats[4] = {P2, P3, P4, P5};
  float sc = scales[lvl];
  int H = Hs[lvl], W = Ws[lvl];
  const float* feat = feats[lvl];

  float bx1 = rx1 * sc, by1 = ry1 * sc;
  float bw = fmaxf(rx2 * sc - bx1, 1.0f) * (1.0f / 7.0f);
  float bh = fmaxf(ry2 * sc - by1, 1.0f) * (1.0f / 7.0f);

  if (lane >= 49) return;
  int oh = (lane * 37) >> 8;  // floor(lane/7) for lane<49
  int ow = lane - oh * 7;

  const float* fc = feat + (size_t)ch * H * W;
  float acc = 0.0f;
#pragma unroll
  for (int sy = 0; sy < 2; ++sy) {
    float py = by1 + ((float)oh + ((float)sy + 0.5f) * 0.5f) * bh;
    float vy = (py > -1.0f && py < (float)H) ? 1.0f : 0.0f;
    float yy = fminf(fmaxf(py, 0.0f), (float)(H - 1));
    float y0f = floorf(yy);
    int y0 = (int)y0f;
    int y1 = min(y0 + 1, H - 1);
    float ly = yy - y0f;
#pragma unroll
    for (int sx = 0; sx < 2; ++sx) {
      float px = bx1 + ((float)ow + ((float)sx + 0.5f) * 0.5f) * bw;
      float v = vy * ((px > -1.0f && px < (float)W) ? 1.0f : 0.0f);
      float xx = fminf(fmaxf(px, 0.0f), (float)(W - 1));
      float x0f = floorf(xx);
      int x0 = (int)x0f;
      int x1 = min(x0 + 1, W - 1);
      float lx = xx - x0f;
      float f00 = fc[y0 * W + x0], f01 = fc[y0 * W + x1];
      float f10 = fc[y1 * W + x0], f11 = fc[y1 * W + x1];
      float bil = f00 * (1.0f - ly) * (1.0f - lx) + f01 * (1.0f - ly) * lx +
                  f10 * ly * (1.0f - lx) + f11 * ly * lx;
      acc += bil * v;
    }
  }
  xout[(size_t)n * KDIM + (size_t)ch * 49 + lane] = (__bf16)(acc * 0.25f);
}

// ---------------------------------------------------------------------------
// 64x64-tile transpose + fp32->bf16: src [R][C] -> dst [C][R].
// float4 reads, 8B bf16x4 writes.
// ---------------------------------------------------------------------------
__global__ __launch_bounds__(256) void transpose_to_bf16_64(
    const float* __restrict__ src, __bf16* __restrict__ dst, int R, int C) {
  __shared__ float tile[64][65];
  int t = threadIdx.x;
  int bc = blockIdx.x * 64, br = blockIdx.y * 64;
  int rr = t >> 4, c4 = (t & 15) * 4;
#pragma unroll
  for (int p = 0; p < 4; ++p) {
    int r = p * 16 + rr;
    f32x4 v = *(const f32x4*)&src[(size_t)(br + r) * C + bc + c4];
    tile[r][c4] = v.x; tile[r][c4 + 1] = v.y;
    tile[r][c4 + 2] = v.z; tile[r][c4 + 3] = v.w;
  }
  __syncthreads();
#pragma unroll
  for (int p = 0; p < 4; ++p) {
    int c = p * 16 + rr;
    int r4 = c4;
    bf16x4 o = {(__bf16)tile[r4][c], (__bf16)tile[r4 + 1][c],
                (__bf16)tile[r4 + 2][c], (__bf16)tile[r4 + 3][c]};
    *(bf16x4*)&dst[(size_t)(bc + c) * R + br + r4] = o;
  }
}

// ---------------------------------------------------------------------------
// Wcls [1024][81] fp32 -> WcT [128][1024] bf16 (rows 81..127 zero).
// grid (16, 2)
// ---------------------------------------------------------------------------
__global__ __launch_bounds__(256) void transpose_pad_cls(
    const float* __restrict__ Wcls, __bf16* __restrict__ WcT) {
  __shared__ float tile[64][65];
  int t = threadIdx.x;
  int bk = blockIdx.x * 64;
  int bj = blockIdx.y * 64;
  int rr = t >> 4, c4 = (t & 15) * 4;
#pragma unroll
  for (int p = 0; p < 4; ++p) {
    int k = bk + p * 16 + rr;
#pragma unroll
    for (int i = 0; i < 4; ++i) {
      int j = bj + c4 + i;
      tile[p * 16 + rr][c4 + i] =
          (j < NUM_CLS) ? Wcls[(size_t)k * NUM_CLS + j] : 0.0f;
    }
  }
  __syncthreads();
#pragma unroll
  for (int p = 0; p < 4; ++p) {
    int c = p * 16 + rr;
    int r4 = c4;
    bf16x4 o = {(__bf16)tile[r4][c], (__bf16)tile[r4 + 1][c],
                (__bf16)tile[r4 + 2][c], (__bf16)tile[r4 + 3][c]};
    *(bf16x4*)&WcT[(size_t)(bj + c) * 1024 + bk + r4] = o;
  }
}

// ---------------------------------------------------------------------------
// m97-style bf16 MFMA GEMM with split-K partials.
// Block tile 128x128, BK=32, 256 threads = 4 waves, each wave 64x64 (4x4 acc
// of 16x16x32). Staging via global_load_lds width=16 with chunk swizzle so
// fragment reads land 16B-aligned at row*64 + ((q + (fr>>1))&3)*16.
// part[z][M][N] fp32.
// ---------------------------------------------------------------------------
__global__ __launch_bounds__(256, 2) void mfma_gemm128(
    const __bf16* __restrict__ A, const __bf16* __restrict__ Bt,
    float* __restrict__ part, int M, int N, int K, int chunk) {
  __shared__ __align__(16) unsigned char smem[16384];
  unsigned char* As = smem;
  unsigned char* Bs = smem + 8192;

  int t = threadIdx.x;
  int wave = t >> 6;
  int lane = t & 63;
  int fr = lane & 15, q = lane >> 4;
  int bm = blockIdx.y * 128, bn = blockIdx.x * 128;
  int wm = (wave >> 1) * 64, wn = (wave & 1) * 64;

  int kbeg = blockIdx.z * chunk;
  int kend = min(K, kbeg + chunk);

  // lane t stages row (t>>2) [+64 for second half], global chunk qsrc, into
  // LDS slot (t&3); slot s of row r holds chunk (s - (r>>1)) & 3.
  int qsrc = ((t & 3) - ((t >> 3) & 3)) & 3;
  const __bf16* a0 = A + (size_t)(bm + (t >> 2)) * K + kbeg + qsrc * 8;
  const __bf16* a1 = a0 + (size_t)64 * K;
  const __bf16* b0 = Bt + (size_t)(bn + (t >> 2)) * K + kbeg + qsrc * 8;
  const __bf16* b1 = b0 + (size_t)64 * K;
  unsigned char* AsW = As + wave * 1024;
  unsigned char* BsW = Bs + wave * 1024;

  int sA = ((q + (fr >> 1)) & 3) * 16;

  f32x4 acc[4][4];
#pragma unroll
  for (int i = 0; i < 4; ++i)
#pragma unroll
    for (int j = 0; j < 4; ++j) acc[i][j] = (f32x4){0.f, 0.f, 0.f, 0.f};

  for (int k0 = kbeg; k0 < kend; k0 += 32) {
    __syncthreads();
    gload16(a0, AsW);
    gload16(a1, AsW + 4096);
    gload16(b0, BsW);
    gload16(b1, BsW + 4096);
    a0 += 32; a1 += 32; b0 += 32; b1 += 32;
    __syncthreads();   // compiler drains vmcnt before s_barrier

    bf16x8 af[4], bfr[4];
#pragma unroll
    for (int i = 0; i < 4; ++i)
      af[i] = *(const bf16x8*)(As + (wm + 16 * i + fr) * 64 + sA);
#pragma unroll
    for (int j = 0; j < 4; ++j)
      bfr[j] = *(const bf16x8*)(Bs + (wn + 16 * j + fr) * 64 + sA);
#pragma unroll
    for (int i = 0; i < 4; ++i)
#pragma unroll
      for (int j = 0; j < 4; ++j)
        acc[i][j] = __builtin_amdgcn_mfma_f32_16x16x32_bf16(af[i], bfr[j],
                                                            acc[i][j], 0, 0, 0);
  }

  float* P = part + (size_t)blockIdx.z * M * N;
#pragma unroll
  for (int i = 0; i < 4; ++i) {
#pragma unroll
    for (int j = 0; j < 4; ++j) {
      int row0 = bm + wm + 16 * i + q * 4;
      int col = bn + wn + 16 * j + fr;
#pragma unroll
      for (int r = 0; r < 4; ++r)
        P[(size_t)(row0 + r) * N + col] = acc[i][j][r];
    }
  }
}

// ---------------------------------------------------------------------------
// out = act(sum_z part[z] + bias); optional fp32 and bf16 outputs.
// Nmask = N-1 (N power of two); bias guarded to bias_n entries.
// ---------------------------------------------------------------------------
__global__ __launch_bounds__(256) void reduce_kernel(
    const float* __restrict__ part, int S, int MN, int Nmask,
    const float* __restrict__ bias, int bias_n, int relu,
    float* __restrict__ outf, __bf16* __restrict__ outb) {
  int i4 = (blockIdx.x * 256 + threadIdx.x) * 4;
  if (i4 >= MN) return;
  f32x4 s = {0.f, 0.f, 0.f, 0.f};
  for (int z = 0; z < S; ++z) {
    f32x4 v = *(const f32x4*)&part[(size_t)z * MN + i4];
    s.x += v.x; s.y += v.y; s.z += v.z; s.w += v.w;
  }
  int col = i4 & Nmask;
  float r[4] = {s.x, s.y, s.z, s.w};
#pragma unroll
  for (int j = 0; j < 4; ++j) {
    float b = (col + j < bias_n) ? bias[col + j] : 0.0f;
    float v = r[j] + b;
    if (relu) v = fmaxf(v, 0.0f);
    r[j] = v;
  }
  if (outf) {
    f32x4 o = {r[0], r[1], r[2], r[3]};
    *(f32x4*)&outf[i4] = o;
  }
  if (outb) {
    bf16x4 o = {(__bf16)r[0], (__bf16)r[1], (__bf16)r[2], (__bf16)r[3]};
    *(bf16x4*)&outb[i4] = o;
  }
}

// ---------------------------------------------------------------------------
// loc_train[n][d] = h2[n] . Wloc[:, label[n]*4+d] + bloc[label[n]*4+d]
// ---------------------------------------------------------------------------
__global__ __launch_bounds__(256) void loc_head_kernel(
    const float* __restrict__ h2, const float* __restrict__ Wloc,
    const float* __restrict__ bloc, const int* __restrict__ label,
    float* __restrict__ loct) {
  int n = blockIdx.x;
  int d = threadIdx.x >> 6;
  int lane = threadIdx.x & 63;
  int lab = label[n];
  const float* h = h2 + (size_t)n * HID;
  const float* w = Wloc + (size_t)lab * 4 + d;
  float s = 0.0f;
#pragma unroll
  for (int i = 0; i < 16; ++i) {
    int k = lane + i * 64;
    s += h[k] * w[(size_t)k * (NUM_CLS * 4)];
  }
#pragma unroll
  for (int off = 32; off > 0; off >>= 1) s += __shfl_down(s, off);
  if (lane == 0) loct[n * 4 + d] = s + bloc[lab * 4 + d];
}

// ---------------------------------------------------------------------------
// Fused loss; logits row stride 128 (padded), cols 0..80 valid.
// ---------------------------------------------------------------------------
__global__ __launch_bounds__(512) void loss_kernel(
    const float* __restrict__ logits, const int* __restrict__ label,
    const float* __restrict__ loct, const float* __restrict__ loc,
    float* __restrict__ out) {
  int t = threadIdx.x;
  const float* row = logits + (size_t)t * 128;
  float m = -1e30f;
  for (int j = 0; j < NUM_CLS; ++j) m = fmaxf(m, row[j]);
  float se = 0.0f;
  for (int j = 0; j < NUM_CLS; ++j) se += expf(row[j] - m);
  float cl = (m + logf(se)) - row[label[t]];

  float a = fabsf(loct[t] - loc[t]);
  float bl = (a < 1.0f) ? 0.5f * a * a : a - 0.5f;

  float v = cl + bl;
#pragma unroll
  for (int off = 32; off > 0; off >>= 1) v += __shfl_down(v, off);

  __shared__ float red[8];
  if ((t & 63) == 0) red[t >> 6] = v;
  __syncthreads();
  if (t == 0) {
    float tot = 0.0f;
    for (int i = 0; i < 8; ++i) tot += red[i];
    out[0] = tot * (1.0f / (float)N_ROI);
  }
}

// ---------------------------------------------------------------------------
extern "C" void kernel_launch(void* const* d_in, const int* in_sizes, int n_in,
                              void* d_out, int out_size, void* d_ws, size_t ws_size,
                              hipStream_t stream) {
  const float* P2   = (const float*)d_in[0];
  const float* P3   = (const float*)d_in[1];
  const float* P4   = (const float*)d_in[2];
  const float* P5   = (const float*)d_in[3];
  const float* rois = (const float*)d_in[4];
  const int*   label= (const int*)d_in[5];
  const float* loc  = (const float*)d_in[6];
  const float* W1   = (const float*)d_in[7];
  const float* b1   = (const float*)d_in[8];
  const float* W2   = (const float*)d_in[9];
  const float* b2   = (const float*)d_in[10];
  const float* Wcls = (const float*)d_in[11];
  const float* bcls = (const float*)d_in[12];
  const float* Wloc = (const float*)d_in[13];
  const float* bloc = (const float*)d_in[14];
  float* out = (float*)d_out;

  char* w = (char*)d_ws;
  __bf16* xb  = (__bf16*)w;  w += (size_t)N_ROI * KDIM * 2;       // 12.8 MB
  __bf16* W1t = (__bf16*)w;  w += (size_t)KDIM * HID * 2;         // 25.7 MB
  __bf16* W2t = (__bf16*)w;  w += (size_t)HID * HID * 2;          // 2.1 MB
  __bf16* WcT = (__bf16*)w;  w += (size_t)128 * HID * 2;          // 0.26 MB
  __bf16* h1b = (__bf16*)w;  w += (size_t)N_ROI * HID * 2;        // 1 MB
  __bf16* h2b = (__bf16*)w;  w += (size_t)N_ROI * HID * 2;        // 1 MB
  float*  h2f = (float*)w;   w += (size_t)N_ROI * HID * 4;        // 2.1 MB
  float*  logits = (float*)w; w += (size_t)N_ROI * 128 * 4;       // 0.26 MB
  float*  loct = (float*)w;  w += (size_t)N_ROI * 4;              // 2 KB
  float*  part = (float*)w;                                       // 32 MB (16 slices)

  transpose_to_bf16_64<<<dim3(HID / 64, KDIM / 64), 256, 0, stream>>>(W1, W1t,
                                                                      KDIM, HID);
  transpose_to_bf16_64<<<dim3(HID / 64, HID / 64), 256, 0, stream>>>(W2, W2t,
                                                                     HID, HID);
  transpose_pad_cls<<<dim3(16, 2), 256, 0, stream>>>(Wcls, WcT);
  roi_align_kernel<<<dim3(N_ROI, 64), 256, 0, stream>>>(P2, P3, P4, P5, rois,
                                                        xb);

  // FC1: [512,12544]@[12544,1024], split-K 16 (chunk 800; last 544)
  mfma_gemm128<<<dim3(HID / 128, N_ROI / 128, 16), 256, 0, stream>>>(
      xb, W1t, part, N_ROI, HID, KDIM, 800);
  reduce_kernel<<<(N_ROI * HID) / 1024, 256, 0, stream>>>(
      part, 16, N_ROI * HID, HID - 1, b1, HID, 1, nullptr, h1b);

  // FC2: [512,1024]@[1024,1024], split-K 8 (chunk 128)
  mfma_gemm128<<<dim3(HID / 128, N_ROI / 128, 8), 256, 0, stream>>>(
      h1b, W2t, part, N_ROI, HID, HID, 128);
  reduce_kernel<<<(N_ROI * HID) / 1024, 256, 0, stream>>>(
      part, 8, N_ROI * HID, HID - 1, b2, HID, 1, h2f, h2b);

  // cls head: [512,1024]@[1024,128pad], split-K 4 (chunk 256)
  mfma_gemm128<<<dim3(1, N_ROI / 128, 4), 256, 0, stream>>>(
      h2b, WcT, part, N_ROI, 128, HID, 256);
  reduce_kernel<<<(N_ROI * 128) / 1024, 256, 0, stream>>>(
      part, 4, N_ROI * 128, 127, bcls, NUM_CLS, 0, logits, nullptr);

  loc_head_kernel<<<N_POS, 256, 0, stream>>>(h2f, Wloc, bloc, label, loct);
  loss_kernel<<<1, 512, 0, stream>>>(logits, label, loct, loc, out);
}